// Round 8
// baseline (355.985 us; speedup 1.0000x reference)
//
#include <hip/hip_runtime.h>
#include <math.h>

#define KK 48
#define TT 1024
#define BB 512
#define START_TAG 46
#define END_TAG 47
#define NS 16            // sentences per block (mfma N dimension)
#define NBLK (BB / NS)   // 32 blocks
#define HT (TT / 2)      // 512 steps per direction

typedef float f32x4 __attribute__((ext_vector_type(4)));
typedef float f32x2v __attribute__((ext_vector_type(2)));
typedef short short8 __attribute__((ext_vector_type(8)));
typedef unsigned u32x4 __attribute__((ext_vector_type(4)));

// pack two fp32 -> one dword of two bf16 (round-half-up; verified in R6)
__device__ __forceinline__ unsigned pack_bf16(float lo, float hi) {
    unsigned ul = __float_as_uint(lo) + 0x8000u;
    unsigned uh = __float_as_uint(hi) + 0x8000u;
    return __builtin_amdgcn_perm(uh, ul, 0x07060302u);   // [ul.hi16, uh.hi16]
}

// Logical tag stored at C-layout slot (mt, q, r). Chosen so that the
// C->B relayout is: B0 = own lane's packed dwords (no cross-lane), B1 =
// own pk[2][h] + shfl_xor(pk[2][h], 32). Logical k-order comes out as the
// IDENTITY, so A-fragments / START injection / feats gather stay natural.
__device__ __forceinline__ int rowmap(int mt, int q, int r) {
    return (mt < 2) ? (8 * q + 4 * mt + r)
                    : (32 + 8 * (q & 1) + 2 * (q >> 1) + (r & 1) + 4 * (r >> 1));
}

// load one feats row's 48 floats for this lane's 12 slots:
// a = rows 8q..8q+3 (mt0), b = 8q+4..8q+7 (mt1), c = mt2 rows (two f32x2)
__device__ __forceinline__ void load_row(const float* __restrict__ base,
                                         int oA, int oC,
                                         f32x4& a, f32x4& b, f32x4& c) {
    a = *(const f32x4*)(base + oA);
    b = *(const f32x4*)(base + oA + 4);
    f32x2v c1 = *(const f32x2v*)(base + oC);
    f32x2v c2 = *(const f32x2v*)(base + oC + 4);
    c = (f32x4){c1.x, c1.y, c2.x, c2.y};
}

// ---------------------------------------------------------------------------
// MFMA-batched bidirectional CRF neg-log-likelihood (R6 structure, LDS-free
// inner loop). 16 sentences per block as columns of X (48x16):
//   fwd: X' = (E @ X) * exp(F_t)        (wave 0)
//   bwd: X' = E^T @ (X * exp(F_t))      (wave 1)
// 6 mfma_f32_16x16x32_bf16 per step. R6's per-step LDS round-trip (~240 cyc
// + 655k bank conflicts) replaced by a row-permuted layout where the C->B
// relayout is 6 packs + 2 shfl_xor(32) — no LDS, no round-trip.
// R7 lesson: v_readlane broadcast has a ~8cyc/op floor (384 cyc/step); this
// kernel has zero readlanes in the loop.
// Z_b = beta_m^T alpha_m at m=T/2; per-column pow-2 rescale every 8 steps
// with exact int ledgers (verified R6, absmax 32 < 90.24 threshold).
// ---------------------------------------------------------------------------
__global__ __launch_bounds__(128)
__attribute__((amdgpu_waves_per_eu(1, 1)))
void crf_kernel(const float* __restrict__ feats,
                const float* __restrict__ trans,
                const int* __restrict__ tags,
                float* __restrict__ out) {
    const int tid = threadIdx.x;
    const int wave = tid >> 6;       // 0 = fwd, 1 = bwd
    const int lane = tid & 63;
    const int n = lane & 15;         // column = sentence within block
    const int q = lane >> 4;         // quad 0..3
    const int blk = blockIdx.x;

    __shared__ float shFin[2][64 * 12];
    __shared__ int shLed[2][NS];
    __shared__ float shGold[NS];

    // ---- A fragments: logical k = identity; m-row = rowmap(mt, n>>2, n&3) ----
    short8 A[3][2];
    {
        const int mr_q = n >> 2, mr_r = n & 3;
        #pragma unroll
        for (int mt = 0; mt < 3; ++mt) {
            const int m = rowmap(mt, mr_q, mr_r);
            #pragma unroll
            for (int kt = 0; kt < 2; ++kt) {
                short8 f = {};
                #pragma unroll
                for (int j = 0; j < 8; ++j) {
                    int k = kt * 32 + q * 8 + j;
                    float v = 0.0f;
                    if (k < KK)
                        v = __expf(wave == 0 ? trans[m * KK + k]
                                             : trans[k * KK + m]);
                    unsigned u = __float_as_uint(v) + 0x8000u;
                    f[j] = (short)(u >> 16);
                }
                A[mt][kt] = f;
            }
        }
    }

    const float* fb = feats + (size_t)(blk * NS + n) * TT * KK;
    const int oA = 8 * q;
    const int oC = 32 + 8 * (q & 1) + 2 * (q >> 1);

    f32x4 X[3];
    f32x4 ring[4][3];
    int led = 0;

    if (wave == 0) {
        // ======================= FORWARD =======================
        short8 B0 = {}, B1 = {};
        if (q == 1) B1[6] = (short)0x3F80;   // alpha_0 = e_START (k=46 identity)

        #pragma unroll
        for (int s = 0; s < 4; ++s)
            load_row(fb + (size_t)s * KK, oA, oC,
                     ring[s][0], ring[s][1], ring[s][2]);

        #pragma unroll 4
        for (int t = 0; t < HT; ++t) {
            f32x4 D[3];
            #pragma unroll
            for (int mt = 0; mt < 3; ++mt) {
                f32x4 c = {0.f, 0.f, 0.f, 0.f};
                c = __builtin_amdgcn_mfma_f32_16x16x32_bf16(A[mt][0], B0, c, 0, 0, 0);
                c = __builtin_amdgcn_mfma_f32_16x16x32_bf16(A[mt][1], B1, c, 0, 0, 0);
                D[mt] = c;
            }
            int sl = t & 3;
            #pragma unroll
            for (int mt = 0; mt < 3; ++mt) {
                f32x4 r = ring[sl][mt];
                X[mt][0] = D[mt][0] * __expf(r[0]);
                X[mt][1] = D[mt][1] * __expf(r[1]);
                X[mt][2] = D[mt][2] * __expf(r[2]);
                X[mt][3] = D[mt][3] * __expf(r[3]);
            }
            load_row(fb + (size_t)(t + 4) * KK, oA, oC,
                     ring[sl][0], ring[sl][1], ring[sl][2]);
            if ((t & 7) == 7) {
                float m = X[0][0];
                #pragma unroll
                for (int mt = 0; mt < 3; ++mt) {
                    m = fmaxf(m, X[mt][0]); m = fmaxf(m, X[mt][1]);
                    m = fmaxf(m, X[mt][2]); m = fmaxf(m, X[mt][3]);
                }
                m = fmaxf(m, __shfl_xor(m, 16, 64));
                m = fmaxf(m, __shfl_xor(m, 32, 64));
                int e0 = ((__float_as_int(m) >> 23) & 0xff) - 127;
                led += e0;
                float sc = __int_as_float((127 - e0) << 23);
                #pragma unroll
                for (int mt = 0; mt < 3; ++mt) {
                    X[mt][0] *= sc; X[mt][1] *= sc;
                    X[mt][2] *= sc; X[mt][3] *= sc;
                }
            }
            // ---- relayout C -> B: 6 packs + 2 shfl_xor(32), no LDS ----
            unsigned p00 = pack_bf16(X[0][0], X[0][1]);
            unsigned p01 = pack_bf16(X[0][2], X[0][3]);
            unsigned p10 = pack_bf16(X[1][0], X[1][1]);
            unsigned p11 = pack_bf16(X[1][2], X[1][3]);
            unsigned p20 = pack_bf16(X[2][0], X[2][1]);
            unsigned p21 = pack_bf16(X[2][2], X[2][3]);
            unsigned s20 = (unsigned)__shfl_xor((int)p20, 32, 64);
            unsigned s21 = (unsigned)__shfl_xor((int)p21, 32, 64);
            u32x4 b0v = {p00, p01, p10, p11};
            u32x4 b1v = {p20, s20, p21, s21};
            if (q >= 2) b1v = (u32x4){0u, 0u, 0u, 0u};   // k=48..63 pad
            B0 = __builtin_bit_cast(short8, b0v);
            B1 = __builtin_bit_cast(short8, b1v);
        }
    } else {
        // ======================= BACKWARD =======================
        #pragma unroll
        for (int mt = 0; mt < 3; ++mt)
            #pragma unroll
            for (int r = 0; r < 4; ++r)
                X[mt][r] = __expf(trans[END_TAG * KK + rowmap(mt, q, r)]);

        #pragma unroll
        for (int s = 0; s < 4; ++s)
            load_row(fb + (size_t)(TT - 1 - s) * KK, oA, oC,
                     ring[s][0], ring[s][1], ring[s][2]);

        #pragma unroll 4
        for (int t = 0; t < HT; ++t) {
            int sl = t & 3;
            f32x4 W[3];
            #pragma unroll
            for (int mt = 0; mt < 3; ++mt) {
                f32x4 r = ring[sl][mt];
                W[mt][0] = X[mt][0] * __expf(r[0]);
                W[mt][1] = X[mt][1] * __expf(r[1]);
                W[mt][2] = X[mt][2] * __expf(r[2]);
                W[mt][3] = X[mt][3] * __expf(r[3]);
            }
            load_row(fb + (size_t)(TT - 5 - t) * KK, oA, oC,
                     ring[sl][0], ring[sl][1], ring[sl][2]);
            if ((t & 7) == 7) {
                float m = W[0][0];
                #pragma unroll
                for (int mt = 0; mt < 3; ++mt) {
                    m = fmaxf(m, W[mt][0]); m = fmaxf(m, W[mt][1]);
                    m = fmaxf(m, W[mt][2]); m = fmaxf(m, W[mt][3]);
                }
                m = fmaxf(m, __shfl_xor(m, 16, 64));
                m = fmaxf(m, __shfl_xor(m, 32, 64));
                int e0 = ((__float_as_int(m) >> 23) & 0xff) - 127;
                led += e0;
                float sc = __int_as_float((127 - e0) << 23);
                #pragma unroll
                for (int mt = 0; mt < 3; ++mt) {
                    W[mt][0] *= sc; W[mt][1] *= sc;
                    W[mt][2] *= sc; W[mt][3] *= sc;
                }
            }
            unsigned p00 = pack_bf16(W[0][0], W[0][1]);
            unsigned p01 = pack_bf16(W[0][2], W[0][3]);
            unsigned p10 = pack_bf16(W[1][0], W[1][1]);
            unsigned p11 = pack_bf16(W[1][2], W[1][3]);
            unsigned p20 = pack_bf16(W[2][0], W[2][1]);
            unsigned p21 = pack_bf16(W[2][2], W[2][3]);
            unsigned s20 = (unsigned)__shfl_xor((int)p20, 32, 64);
            unsigned s21 = (unsigned)__shfl_xor((int)p21, 32, 64);
            u32x4 b0v = {p00, p01, p10, p11};
            u32x4 b1v = {p20, s20, p21, s21};
            if (q >= 2) b1v = (u32x4){0u, 0u, 0u, 0u};
            short8 B0 = __builtin_bit_cast(short8, b0v);
            short8 B1 = __builtin_bit_cast(short8, b1v);
            #pragma unroll
            for (int mt = 0; mt < 3; ++mt) {
                f32x4 c = {0.f, 0.f, 0.f, 0.f};
                c = __builtin_amdgcn_mfma_f32_16x16x32_bf16(A[mt][0], B0, c, 0, 0, 0);
                c = __builtin_amdgcn_mfma_f32_16x16x32_bf16(A[mt][1], B1, c, 0, 0, 0);
                X[mt] = c;
            }
        }
    }

    // ---- dump final state + ledgers ----
    #pragma unroll
    for (int mt = 0; mt < 3; ++mt)
        #pragma unroll
        for (int r = 0; r < 4; ++r)
            shFin[wave][lane * 12 + mt * 4 + r] = X[mt][r];
    if (lane < NS) shLed[wave][lane] = led;

    // ---- gold score: sentence s = tid/8, t-chunk c = tid%8 (R6-verified) ----
    {
        int s = tid >> 3;
        int c = tid & 7;
        const int* tg = tags + (size_t)(blk * NS + s) * TT;
        const float* fs = feats + (size_t)(blk * NS + s) * TT * KK;
        float g = 0.0f;
        int tbeg = c * 128;
        #pragma unroll 4
        for (int t = tbeg; t < tbeg + 128; ++t) {
            int cur = tg[t];
            int prev = (t == 0) ? START_TAG : tg[t - 1];
            g += trans[cur * KK + prev] + fs[(size_t)t * KK + cur];
        }
        if (c == 0) g += trans[END_TAG * KK + tg[TT - 1]];
        g += __shfl_xor(g, 1, 64);
        g += __shfl_xor(g, 2, 64);
        g += __shfl_xor(g, 4, 64);
        if (c == 0) shGold[s] = g;
    }

    __syncthreads();

    // ---- combine: both waves share the same rowmap, so slots align ----
    if (wave == 0 && lane < NS) {
        float dot = 0.0f;
        #pragma unroll
        for (int qq = 0; qq < 4; ++qq)
            #pragma unroll
            for (int mt = 0; mt < 3; ++mt)
                #pragma unroll
                for (int r = 0; r < 4; ++r) {
                    int idx = (qq * 16 + lane) * 12 + mt * 4 + r;
                    dot += shFin[0][idx] * shFin[1][idx];
                }
        float logz = logf(dot) +
                     (float)(shLed[0][lane] + shLed[1][lane]) * 0.6931471805599453f;
        out[blk * NS + lane] = logz - shGold[lane];
    }
}

extern "C" void kernel_launch(void* const* d_in, const int* in_sizes, int n_in,
                              void* d_out, int out_size, void* d_ws, size_t ws_size,
                              hipStream_t stream) {
    const float* feats = (const float*)d_in[0];
    const float* trans = (const float*)d_in[1];
    const int* tags = (const int*)d_in[2];
    float* out = (float*)d_out;

    crf_kernel<<<NBLK, 128, 0, stream>>>(feats, trans, tags, out);
}

// Round 9
// 255.303 us; speedup vs baseline: 1.3944x; 1.3944x over previous
//
#include <hip/hip_runtime.h>
#include <math.h>

#define KK 48
#define TT 1024
#define BB 512
#define START_TAG 46
#define END_TAG 47
#define HGRP (TT / 2 / 4)   // 128 groups of 4 steps per half

typedef _Float16 h2 __attribute__((ext_vector_type(2)));

#if defined(__has_builtin)
#if __has_builtin(__builtin_amdgcn_fdot2)
#define HAVE_FDOT2 1
#endif
#endif

// v_dot2_f32_f16: c + a.x*b.x + a.y*b.y (f32 accumulate)
__device__ __forceinline__ float fdot2(h2 a, h2 b, float c) {
#ifdef HAVE_FDOT2
    return __builtin_amdgcn_fdot2(a, b, c, false);
#else
    return c + (float)a.x * (float)b.x + (float)a.y * (float)b.y;
#endif
}

// ---------------------------------------------------------------------------
// Bidirectional CRF neg-log-likelihood, two waves per sentence (R5 skeleton).
//
//   Z = beta_m^T * alpha_m   (exact, m = T/2)
//   alpha_t = diag(ef_t) E alpha_{t-1}        (wave 0, rows 0..511)
//   beta_{t-1} = E^T diag(ef_t) beta_t        (wave 1, rows 1023..512)
//
// R5 ran 787 cyc/step: ~315 issue (48 readlane + 48 fma + misc @2cyc) plus
// ~470 stall that scales with the readlane/fma count (R7 falsified chain-depth
// and scheduling theories; R6/R8 falsified MFMA batching — TLP loss kills it).
// R9 halves the per-step op count: alpha crosses the wave as 24 packed-f16
// dwords (24 readlanes) consumed directly by 24 v_dot2_f32_f16 (f32 accum).
// Pack = 1 DPP quad-perm partner swap + 2 cndmask + 1 cvt_pkrtz (RTZ clips,
// never infs). f16 range forces rescale EVERY step: uniform pow-2 scale from
// exponent of readlane(s,0), exact int ledger (absmax-0 scheme from R1-R5).
// E in f16: systematic err ~2^-11 -> ~0.1 absolute on O(4000) outputs
// (threshold 90.24). exp(-1e5)==0 masks START-row/END-col for free.
// ---------------------------------------------------------------------------

template <bool FWD>
__device__ __forceinline__ void run_half(const float* __restrict__ fb,
                                         const float* __restrict__ trans,
                                         int ci, bool evenLane,
                                         float& sOut, int& esumOut) {
    // E for this direction in f16 pairs: fwd row ci, bwd col ci
    h2 Eh[24];
    #pragma unroll
    for (int c = 0; c < 24; ++c) {
        float e0 = __expf(FWD ? trans[ci * KK + 2 * c] : trans[(2 * c) * KK + ci]);
        float e1 = __expf(FWD ? trans[ci * KK + 2 * c + 1] : trans[(2 * c + 1) * KK + ci]);
        Eh[c] = (h2){(_Float16)e0, (_Float16)e1};
    }

    float s = FWD ? 0.0f : __expf(trans[END_TAG * KK + ci]);  // bwd: beta_T[ci]

    // wave-uniform alpha/beta broadcast state, f16-pair packed
    int au[24];
    #pragma unroll
    for (int c = 0; c < 24; ++c) au[c] = (c == 23) ? 0x00003C00 : 0;  // e_START

    int esum = 0;

    // feats prefetch: groups of 4 rows; fwd ascending, bwd descending
    float fr[4];
    #pragma unroll
    for (int k = 0; k < 4; ++k) {
        int row = FWD ? k : (TT - 1 - k);
        fr[k] = fb[row * KK + ci];
    }

    for (int g = 0; g < HGRP; ++g) {
        float fn[4] = {0.f, 0.f, 0.f, 0.f};
        if (g < HGRP - 1) {
            #pragma unroll
            for (int k = 0; k < 4; ++k) {
                int row = FWD ? ((g + 1) * 4 + k) : (TT - 1 - (g + 1) * 4 - k);
                fn[k] = fb[row * KK + ci];
            }
        }
        float ef[4];
        #pragma unroll
        for (int k = 0; k < 4; ++k) ef[k] = __expf(fr[k]);

        #pragma unroll
        for (int k = 0; k < 4; ++k) {
            if (FWD) {
                // s_i = sum_c dot2(Eh[c], au[c]) : 4 chains x 6
                float a0 = 0.f, a1 = 0.f, a2 = 0.f, a3 = 0.f;
                #pragma unroll
                for (int c = 0; c < 6; ++c) {
                    a0 = fdot2(Eh[4 * c + 0], __builtin_bit_cast(h2, au[4 * c + 0]), a0);
                    a1 = fdot2(Eh[4 * c + 1], __builtin_bit_cast(h2, au[4 * c + 1]), a1);
                    a2 = fdot2(Eh[4 * c + 2], __builtin_bit_cast(h2, au[4 * c + 2]), a2);
                    a3 = fdot2(Eh[4 * c + 3], __builtin_bit_cast(h2, au[4 * c + 3]), a3);
                }
                float sr = ((a0 + a1) + (a2 + a3)) * ef[k];
                // uniform pow-2 rescale EVERY step (f16 range), exact ledger
                int rl0 = __builtin_amdgcn_readlane(__float_as_int(sr), 0);
                int e0 = ((rl0 >> 23) & 0xff) - 127;
                esum += e0;
                s = sr * __int_as_float((127 - e0) << 23);
                // pack pair {s_2c, s_2c+1} via DPP partner swap, broadcast 24 dwords
                int pb = __builtin_amdgcn_update_dpp(
                    0, __float_as_int(s), 0xB1, 0xF, 0xF, true);  // quad_perm 1,0,3,2
                float pv = __int_as_float(pb);
                float lo = evenLane ? s : pv;
                float hi = evenLane ? pv : s;
                int pkb = __builtin_bit_cast(int, __builtin_amdgcn_cvt_pkrtz(lo, hi));
                #pragma unroll
                for (int c = 0; c < 24; ++c)
                    au[c] = __builtin_amdgcn_readlane(pkb, 2 * c);
            } else {
                float wr = s * ef[k];
                int rl0 = __builtin_amdgcn_readlane(__float_as_int(wr), 0);
                int e0 = ((rl0 >> 23) & 0xff) - 127;
                esum += e0;
                float w = wr * __int_as_float((127 - e0) << 23);
                int pb = __builtin_amdgcn_update_dpp(
                    0, __float_as_int(w), 0xB1, 0xF, 0xF, true);
                float pv = __int_as_float(pb);
                float lo = evenLane ? w : pv;
                float hi = evenLane ? pv : w;
                int pkb = __builtin_bit_cast(int, __builtin_amdgcn_cvt_pkrtz(lo, hi));
                #pragma unroll
                for (int c = 0; c < 24; ++c)
                    au[c] = __builtin_amdgcn_readlane(pkb, 2 * c);
                float a0 = 0.f, a1 = 0.f, a2 = 0.f, a3 = 0.f;
                #pragma unroll
                for (int c = 0; c < 6; ++c) {
                    a0 = fdot2(Eh[4 * c + 0], __builtin_bit_cast(h2, au[4 * c + 0]), a0);
                    a1 = fdot2(Eh[4 * c + 1], __builtin_bit_cast(h2, au[4 * c + 1]), a1);
                    a2 = fdot2(Eh[4 * c + 2], __builtin_bit_cast(h2, au[4 * c + 2]), a2);
                    a3 = fdot2(Eh[4 * c + 3], __builtin_bit_cast(h2, au[4 * c + 3]), a3);
                }
                s = (a0 + a1) + (a2 + a3);
            }
        }
        #pragma unroll
        for (int k = 0; k < 4; ++k) fr[k] = fn[k];
    }
    sOut = s;        // fwd: alpha_512[lane]*2^-esum;  bwd: beta_512[lane]*2^-esum
    esumOut = esum;
}

__global__ __launch_bounds__(128)
__attribute__((amdgpu_waves_per_eu(1, 1)))
void crf_kernel(const float* __restrict__ feats,
                const float* __restrict__ trans,
                const int* __restrict__ tags,
                float* __restrict__ out) {
    const int b = blockIdx.x;
    const int tid = threadIdx.x;
    const int wave = tid >> 6;          // 0 = forward, 1 = backward
    const int lane = tid & 63;
    const int ci = (lane < KK) ? lane : 0;
    const bool evenLane = (lane & 1) == 0;
    const float* fb = feats + (size_t)b * TT * KK;
    const int* tg = tags + b * TT;

    __shared__ float sh[128];
    __shared__ int shE[2];
    __shared__ float shG[2];

    float sLast; int esum;
    if (wave == 0) run_half<true>(fb, trans, ci, evenLane, sLast, esum);
    else           run_half<false>(fb, trans, ci, evenLane, sLast, esum);

    sh[tid] = sLast;
    if (lane == 0) shE[wave] = esum;

    // ---- gold gather: 1024 t's over 128 threads, after the hot loop ----
    float gacc = 0.0f;
    #pragma unroll
    for (int r = 0; r < TT / 128; ++r) {
        int t = tid + r * 128;
        int cur = tg[t];
        int prev = (t == 0) ? START_TAG : tg[t - 1];
        gacc += trans[cur * KK + prev] + fb[t * KK + cur];
    }
    #pragma unroll
    for (int off = 32; off; off >>= 1) gacc += __shfl_xor(gacc, off, 64);
    if (lane == 0) shG[wave] = gacc;

    __syncthreads();

    if (wave == 0) {
        // Z = sum_i alpha_m[i] * beta_m[i]   (exponent ledgers add)
        float val = (lane < KK) ? sh[lane] * sh[64 + lane] : 0.0f;
        #pragma unroll
        for (int off = 32; off; off >>= 1) val += __shfl_xor(val, off, 64);
        if (lane == 0) {
            float logz = __logf(val) +
                         (float)(shE[0] + shE[1]) * 0.6931471805599453f;
            float gold = shG[0] + shG[1] + trans[END_TAG * KK + tg[TT - 1]];
            out[b] = logz - gold;
        }
    }
}

extern "C" void kernel_launch(void* const* d_in, const int* in_sizes, int n_in,
                              void* d_out, int out_size, void* d_ws, size_t ws_size,
                              hipStream_t stream) {
    const float* feats = (const float*)d_in[0];
    const float* trans = (const float*)d_in[1];
    const int* tags = (const int*)d_in[2];
    float* out = (float*)d_out;

    crf_kernel<<<BB, 128, 0, stream>>>(feats, trans, tags, out);
}